// Round 5
// baseline (1994.628 us; speedup 1.0000x reference)
//
#include <hip/hip_runtime.h>
#include <hip/hip_bf16.h>
#include <math.h>

#define N_DOC 4
#define C_    1024
#define D_    768
#define H_    12
#define E_    40
#define M_    3
#define P_    800
#define NP_   3200
#define EMB_  768
#define NREL_ 97
#define IN2_  1536   // 2*D
#define NPART 24     // 12 k-blocks x 2 b-halves

// ---------------------------------------------------------------- A: ent_emb
__global__ void k_ent_emb(const float* __restrict__ seq, const int* __restrict__ mpos,
                          float* __restrict__ ent_emb) {
  int ne = blockIdx.x;                 // 0..159
  int n = ne / E_, e = ne % E_;
  int base = (n * E_ + e) * M_;
  int p0 = mpos[base + 0] + 1, p1 = mpos[base + 1] + 1, p2 = mpos[base + 2] + 1;
  const float* s0 = seq + ((size_t)n * C_ + p0) * D_;
  const float* s1 = seq + ((size_t)n * C_ + p1) * D_;
  const float* s2 = seq + ((size_t)n * C_ + p2) * D_;
  float* out = ent_emb + (size_t)ne * D_;
  for (int d = threadIdx.x; d < D_; d += blockDim.x) {
    double a = s0[d], b = s1[d], c = s2[d];
    double mx = fmax(a, fmax(b, c));
    double s = exp(a - mx) + exp(b - mx) + exp(c - mx);
    out[d] = (float)(mx + log(s));
  }
}

// ---------------------------------------------------------------- B: ent_att
__global__ void k_ent_att(const float* __restrict__ att, const int* __restrict__ mpos,
                          float* __restrict__ ent_att) {
  int idx = blockIdx.x * 256 + threadIdx.x;        // exactly N*E*H*C = 1966080
  int c = idx & (C_ - 1);
  int h = (idx >> 10) % H_;
  int rem = idx / (C_ * H_);
  int e = rem % E_;
  int n = rem / E_;
  int base = (n * E_ + e) * M_;
  float acc = 0.f;
#pragma unroll
  for (int m = 0; m < M_; ++m) {
    int p = mpos[base + m] + 1;
    acc += att[(((size_t)n * H_ + h) * C_ + p) * C_ + c];
  }
  ent_att[idx] = acc / 3.0f;
}

// ---------------------------------------------------------------- C: ht_att
// 64-thread blocks, float4 loads, wave shfl reduce.
__global__ void k_ht_att(const float* __restrict__ ent_att, const int* __restrict__ hts,
                         float* __restrict__ ht) {
  int np = blockIdx.x;                 // 0..3199
  int n = np / P_;
  int hi = hts[np * 2 + 0], ti = hts[np * 2 + 1];
  const float* ea_h = ent_att + (size_t)(n * E_ + hi) * H_ * C_;
  const float* ea_t = ent_att + (size_t)(n * E_ + ti) * H_ * C_;
  const int t = threadIdx.x;           // 0..63
  float4 v[4];
  float local = 0.f;
#pragma unroll
  for (int q = 0; q < 4; ++q) {
    int c = t * 4 + 256 * q;
    float4 a = {0.f, 0.f, 0.f, 0.f};
#pragma unroll
    for (int h = 0; h < H_; ++h) {
      float4 x = *(const float4*)(ea_h + (size_t)h * C_ + c);
      float4 y = *(const float4*)(ea_t + (size_t)h * C_ + c);
      a.x += x.x * y.x; a.y += x.y * y.y; a.z += x.z * y.z; a.w += x.w * y.w;
    }
    a.x /= 12.f; a.y /= 12.f; a.z /= 12.f; a.w /= 12.f;
    v[q] = a;
    local += a.x + a.y + a.z + a.w;
  }
  float s = local;
#pragma unroll
  for (int m = 32; m > 0; m >>= 1) s += __shfl_xor(s, m);
  float S = s + 1e-5f;
#pragma unroll
  for (int q = 0; q < 4; ++q) {
    int c = t * 4 + 256 * q;
    float4 o;
    o.x = v[q].x / S; o.y = v[q].y / S; o.z = v[q].z / S; o.w = v[q].w / S;
    *(float4*)&ht[(size_t)np * C_ + c] = o;
  }
}

// ---------------------------------------------------------------- D: rs GEMM
// tile 4p x 2o per thread, grid (200,6) -> 4800 waves. Sum order unchanged.
__global__ void k_rs(const float* __restrict__ ht, const float* __restrict__ seq,
                     float* __restrict__ rs) {
  const int pt0 = blockIdx.x * 16;
  const int n = pt0 / P_;
  const int ot = threadIdx.x & 63;
  const int jt = threadIdx.x >> 6;     // 0..3
  const int o0 = blockIdx.y * 128 + ot;
  __shared__ float hlds[16 * 66];
  float a32[4][2];
  double a64[4][2];
#pragma unroll
  for (int q = 0; q < 4; ++q)
#pragma unroll
    for (int i = 0; i < 2; ++i) { a32[q][i] = 0.f; a64[q][i] = 0.0; }
  const float* seqn = seq + (size_t)n * C_ * D_;
  for (int c0 = 0; c0 < C_; c0 += 64) {
    for (int l = threadIdx.x; l < 1024; l += 256) {
      int j = l >> 6, cc = l & 63;
      hlds[j * 66 + cc] = ht[(size_t)(pt0 + j) * C_ + c0 + cc];
    }
    __syncthreads();
#pragma unroll 4
    for (int cc = 0; cc < 64; ++cc) {
      float sv[2];
#pragma unroll
      for (int i = 0; i < 2; ++i) sv[i] = seqn[(size_t)(c0 + cc) * D_ + o0 + 64 * i];
#pragma unroll
      for (int q = 0; q < 4; ++q) {
        float w = hlds[(jt * 4 + q) * 66 + cc];
#pragma unroll
        for (int i = 0; i < 2; ++i) a32[q][i] += w * sv[i];
      }
    }
#pragma unroll
    for (int q = 0; q < 4; ++q)
#pragma unroll
      for (int i = 0; i < 2; ++i) { a64[q][i] += (double)a32[q][i]; a32[q][i] = 0.f; }
    __syncthreads();
  }
#pragma unroll
  for (int q = 0; q < 4; ++q) {
    int p = pt0 + jt * 4 + q;
#pragma unroll
    for (int i = 0; i < 2; ++i)
      rs[(size_t)p * D_ + o0 + 64 * i] = (float)a64[q][i];
  }
}

// ---------------------------------------------------------------- E: zh / zt
// tile 4p x 2o per thread, grid (200,6). Sum order unchanged.
__global__ void k_zht(const float* __restrict__ ent_emb, const float* __restrict__ rs,
                      const int* __restrict__ hts, const float* __restrict__ W,
                      const float* __restrict__ bias, float* __restrict__ out,
                      int which, int dbl_tanh) {
  const int pt0 = blockIdx.x * 16;
  const int n = pt0 / P_;
  const int ot = threadIdx.x & 63;
  const int jt = threadIdx.x >> 6;
  const int o0 = blockIdx.y * 128 + ot;
  __shared__ float xlds[16 * 66];
  __shared__ int sidx[16];
  if (threadIdx.x < 16) sidx[threadIdx.x] = hts[(pt0 + threadIdx.x) * 2 + which];
  float a32[4][2];
  double a64[4][2];
#pragma unroll
  for (int q = 0; q < 4; ++q)
#pragma unroll
    for (int i = 0; i < 2; ++i) { a32[q][i] = 0.f; a64[q][i] = 0.0; }
  __syncthreads();
  for (int k0 = 0; k0 < IN2_; k0 += 64) {
    for (int l = threadIdx.x; l < 1024; l += 256) {
      int j = l >> 6, q = l & 63;
      int kx = k0 + q;
      float val;
      if (kx < D_) val = ent_emb[(size_t)(n * E_ + sidx[j]) * D_ + kx];
      else         val = rs[(size_t)(pt0 + j) * D_ + (kx - D_)];
      xlds[j * 66 + q] = val;
    }
    __syncthreads();
#pragma unroll 4
    for (int q = 0; q < 64; ++q) {
      float wv[2];
#pragma unroll
      for (int i = 0; i < 2; ++i) wv[i] = W[(size_t)(k0 + q) * EMB_ + o0 + 64 * i];
#pragma unroll
      for (int j = 0; j < 4; ++j) {
        float x = xlds[(jt * 4 + j) * 66 + q];
#pragma unroll
        for (int i = 0; i < 2; ++i) a32[j][i] += x * wv[i];
      }
    }
#pragma unroll
    for (int j = 0; j < 4; ++j)
#pragma unroll
      for (int i = 0; i < 2; ++i) { a64[j][i] += (double)a32[j][i]; a32[j][i] = 0.f; }
    __syncthreads();
  }
#pragma unroll
  for (int j = 0; j < 4; ++j) {
    int p = pt0 + jt * 4 + j;
#pragma unroll
    for (int i = 0; i < 2; ++i) {
      int o = o0 + 64 * i;
      double z = a64[j][i] + (double)bias[o];
      z = tanh(z);
      if (dbl_tanh) z = tanh(z);
      out[(size_t)p * EMB_ + o] = (float)z;
    }
  }
}

// ---------------------------------------------------------------- F: logits partial (r 0..95)
// Pipelined: W staged in quarter-slices (16 c x 97 r), double-buffered; zt tile
// resident in LDS. One barrier per phase; prefetch of phase ph+1 overlaps the
// ~2000-cycle FMA stream of phase ph. Summation order (c asc within b, b asc)
// bit-identical to round-4 partials.
__global__ __launch_bounds__(128) void k_logits_part(
    const float* __restrict__ zh, const float* __restrict__ zt,
    const float* __restrict__ Wb, float* __restrict__ part) {
  const int bid = blockIdx.x;          // 0..1199
  const int s   = bid % 24;            // slab = k*2+bh  (XCD s%8 affinity)
  const int t   = bid / 24;            // p-tile 0..49
  const int k   = s >> 1, bh = s & 1;
  const int pt0 = t * 64;
  const int rt = threadIdx.x & 15;
  const int pg = threadIdx.x >> 4;     // 0..7 -> pairs pg*8+j
  const int kb0 = k * 64 + bh * 32;

  __shared__ float Wl[2][16 * 97];     // 2 x 6208 B quarter-slices
  __shared__ float ztl[64][68];        // 17408 B; total LDS 29824 -> 5 blk/CU

  // ---- stage zt tile (once): 64 pairs x 64 c
  {
    int p = threadIdx.x >> 1, half = threadIdx.x & 1;
    const float* src = zt + (size_t)(pt0 + p) * EMB_ + k * 64 + half * 32;
#pragma unroll
    for (int i = 0; i < 8; ++i)
      *(float4*)&ztl[p][half * 32 + i * 4] = *(const float4*)(src + i * 4);
  }

  // ---- W quarter-slice stagers (388 float4 per slice)
  auto stage_regs = [&](int ph, float4* wreg) {
    int b = ph >> 2, cq = ph & 3;
    const float4* src = (const float4*)(Wb + (size_t)((kb0 + b) * 64 + cq * 16) * NREL_);
    wreg[0] = src[threadIdx.x];
    wreg[1] = src[threadIdx.x + 128];
    wreg[2] = src[threadIdx.x + 256];
    if (threadIdx.x < 4) wreg[3] = src[384 + threadIdx.x];
  };
  auto write_lds = [&](float* dst, const float4* wreg) {
    *(float4*)&dst[threadIdx.x * 4] = wreg[0];
    *(float4*)&dst[(threadIdx.x + 128) * 4] = wreg[1];
    *(float4*)&dst[(threadIdx.x + 256) * 4] = wreg[2];
    if (threadIdx.x < 4) *(float4*)&dst[(384 + threadIdx.x) * 4] = wreg[3];
  };

  float4 w0[4];
  stage_regs(0, w0);
  write_lds(Wl[0], w0);
  __syncthreads();

  float acc[8][6];
#pragma unroll
  for (int j = 0; j < 8; ++j)
#pragma unroll
    for (int i = 0; i < 6; ++i) acc[j][i] = 0.f;

  const float* zh_g = zh + (size_t)(pt0 + pg * 8) * EMB_ + kb0;
  float zhv[8];

  for (int ph = 0; ph < 128; ++ph) {   // phase = (b, c-quarter)
    const int cur = ph & 1;
    float4 wn[4];
    if (ph < 127) stage_regs(ph + 1, wn);
    if ((ph & 3) == 0) {
      int b = ph >> 2;
#pragma unroll
      for (int j = 0; j < 8; ++j) zhv[j] = zh_g[(size_t)j * EMB_ + b];
    }
    const int cbase = (ph & 3) * 16;
#pragma unroll
    for (int c4 = 0; c4 < 16; c4 += 4) {
      float4 pz[8];
#pragma unroll
      for (int j = 0; j < 8; ++j) {
        float4 z = *(const float4*)&ztl[pg * 8 + j][cbase + c4];
        pz[j].x = zhv[j] * z.x; pz[j].y = zhv[j] * z.y;
        pz[j].z = zhv[j] * z.z; pz[j].w = zhv[j] * z.w;
      }
      const float* wr = &Wl[cur][c4 * 97];
#pragma unroll
      for (int cc = 0; cc < 4; ++cc) {
#pragma unroll
        for (int i = 0; i < 6; ++i) {
          float w = wr[cc * 97 + rt + 16 * i];
#pragma unroll
          for (int j = 0; j < 8; ++j) {
            float pzc = (cc == 0) ? pz[j].x : (cc == 1) ? pz[j].y
                      : (cc == 2) ? pz[j].z : pz[j].w;
            acc[j][i] += pzc * w;
          }
        }
      }
    }
    if (ph < 127) write_lds(Wl[cur ^ 1], wn);
    __syncthreads();
  }

  float* po = part + (size_t)s * NP_ * NREL_;
#pragma unroll
  for (int j = 0; j < 8; ++j) {
    int p = pt0 + pg * 8 + j;
#pragma unroll
    for (int i = 0; i < 6; ++i)
      po[(size_t)p * NREL_ + rt + 16 * i] = acc[j][i];
  }
}

// ---------------------------------------------------------------- F2: r=96 column
__global__ void k_r96(const float* __restrict__ zh, const float* __restrict__ zt,
                      const float* __restrict__ Wb, float* __restrict__ part) {
  const int pt0 = blockIdx.x * 64;
  const int k  = blockIdx.y;
  const int bh = blockIdx.z;
  const int p = pt0 + (threadIdx.x >> 1);
  const int ch = threadIdx.x & 1;
  const int kb0 = k * 64 + bh * 32;
  const float* zhr = zh + (size_t)p * EMB_ + kb0;
  const float* ztr = zt + (size_t)p * EMB_ + k * 64 + ch * 32;
  float acc = 0.f;
  for (int b = 0; b < 32; ++b) {
    float zhb = zhr[b];
    const float* w = Wb + (size_t)((kb0 + b) * 64 + ch * 32) * NREL_ + 96;
#pragma unroll 8
    for (int c = 0; c < 32; ++c)
      acc += zhb * ztr[c] * w[(size_t)c * NREL_];
  }
  acc += __shfl_xor(acc, 1);
  if (ch == 0)
    part[(size_t)(k * 2 + bh) * NP_ * NREL_ + (size_t)p * NREL_ + 96] = acc;
}

// ---------------------------------------------------------------- G: finalize
__global__ void k_final(const float* __restrict__ part, const float* __restrict__ bb,
                        float* __restrict__ out) {
  const int p = blockIdx.x;
  const int r = threadIdx.x;           // 128 threads
  __shared__ double th_s;
  __shared__ int cnt[128];
  double v = 0.0;
  if (r < NREL_) {
#pragma unroll
    for (int g = 0; g < NPART; ++g)
      v += (double)part[(size_t)g * NP_ * NREL_ + (size_t)p * NREL_ + r];
    v += (double)bb[r];
    out[(size_t)p * NREL_ + r] = (float)v;
  }
  if (r == 0) th_s = v;
  __syncthreads();
  int pred = (r >= 1 && r < NREL_ && v > th_s) ? 1 : 0;
  cnt[r] = pred;
  __syncthreads();
  for (int s = 64; s > 0; s >>= 1) {
    if (r < s) cnt[r] += cnt[r + s];
    __syncthreads();
  }
  if (r < NREL_) {
    float pv = (r == 0) ? ((cnt[0] == 0) ? 1.f : 0.f) : (float)pred;
    out[(size_t)NP_ * NREL_ + (size_t)p * NREL_ + r] = pv;
  }
}

extern "C" void kernel_launch(void* const* d_in, const int* in_sizes, int n_in,
                              void* d_out, int out_size, void* d_ws, size_t ws_size,
                              hipStream_t stream) {
  const float* seq  = (const float*)d_in[0];
  const float* att  = (const float*)d_in[1];
  const int*   mpos = (const int*)d_in[2];
  const int*   hts  = (const int*)d_in[3];
  const float* Wh   = (const float*)d_in[4];
  const float* bh   = (const float*)d_in[5];
  const float* Wt   = (const float*)d_in[6];
  const float* bt   = (const float*)d_in[7];
  const float* Wb   = (const float*)d_in[8];
  const float* bb   = (const float*)d_in[9];
  float* out = (float*)d_out;
  float* ws = (float*)d_ws;

  float* ent_emb = ws;                   // [0, 122880)
  float* ent_att = ws + 122880;          // dead after k_ht_att
  float* ht      = ws + 2088960;         // dead after k_rs
  float* rs      = ws + 5365760;         // dead after k_zht
  float* zh      = ws + 7823360;
  float* zt      = ws + 10280960;
  // part (24*3200*97 floats) aliases dead ent_att+ht+rs: [122880, 7572480)
  float* part    = ws + 122880;

  k_ent_emb<<<160, 256, 0, stream>>>(seq, mpos, ent_emb);
  k_ent_att<<<7680, 256, 0, stream>>>(att, mpos, ent_att);
  k_ht_att<<<3200, 64, 0, stream>>>(ent_att, hts, ht);
  k_rs<<<dim3(200, 6), 256, 0, stream>>>(ht, seq, rs);
  k_zht<<<dim3(200, 6), 256, 0, stream>>>(ent_emb, rs, hts, Wh, bh, zh, 0, 1);
  k_zht<<<dim3(200, 6), 256, 0, stream>>>(ent_emb, rs, hts, Wt, bt, zt, 1, 0);
  k_logits_part<<<1200, 128, 0, stream>>>(zh, zt, Wb, part);
  k_r96<<<dim3(50, 12, 2), 128, 0, stream>>>(zh, zt, Wb, part);
  k_final<<<3200, 128, 0, stream>>>(part, bb, out);
}

// Round 6
// 1522.177 us; speedup vs baseline: 1.3104x; 1.3104x over previous
//
#include <hip/hip_runtime.h>
#include <hip/hip_bf16.h>
#include <math.h>

#define N_DOC 4
#define C_    1024
#define D_    768
#define H_    12
#define E_    40
#define M_    3
#define P_    800
#define NP_   3200
#define EMB_  768
#define NREL_ 97
#define IN2_  1536   // 2*D
#define NPART 24     // 12 k-blocks x 2 b-halves

// ---------------------------------------------------------------- A: ent_emb
__global__ void k_ent_emb(const float* __restrict__ seq, const int* __restrict__ mpos,
                          float* __restrict__ ent_emb) {
  int ne = blockIdx.x;                 // 0..159
  int n = ne / E_, e = ne % E_;
  int base = (n * E_ + e) * M_;
  int p0 = mpos[base + 0] + 1, p1 = mpos[base + 1] + 1, p2 = mpos[base + 2] + 1;
  const float* s0 = seq + ((size_t)n * C_ + p0) * D_;
  const float* s1 = seq + ((size_t)n * C_ + p1) * D_;
  const float* s2 = seq + ((size_t)n * C_ + p2) * D_;
  float* out = ent_emb + (size_t)ne * D_;
  for (int d = threadIdx.x; d < D_; d += blockDim.x) {
    double a = s0[d], b = s1[d], c = s2[d];
    double mx = fmax(a, fmax(b, c));
    double s = exp(a - mx) + exp(b - mx) + exp(c - mx);
    out[d] = (float)(mx + log(s));
  }
}

// ---------------------------------------------------------------- B: ent_att
__global__ void k_ent_att(const float* __restrict__ att, const int* __restrict__ mpos,
                          float* __restrict__ ent_att) {
  int idx = blockIdx.x * 256 + threadIdx.x;        // exactly N*E*H*C = 1966080
  int c = idx & (C_ - 1);
  int h = (idx >> 10) % H_;
  int rem = idx / (C_ * H_);
  int e = rem % E_;
  int n = rem / E_;
  int base = (n * E_ + e) * M_;
  float acc = 0.f;
#pragma unroll
  for (int m = 0; m < M_; ++m) {
    int p = mpos[base + m] + 1;
    acc += att[(((size_t)n * H_ + h) * C_ + p) * C_ + c];
  }
  ent_att[idx] = acc / 3.0f;
}

// ---------------------------------------------------------------- C: ht_att
// 64-thread blocks, float4 loads, wave shfl reduce.
__global__ void k_ht_att(const float* __restrict__ ent_att, const int* __restrict__ hts,
                         float* __restrict__ ht) {
  int np = blockIdx.x;                 // 0..3199
  int n = np / P_;
  int hi = hts[np * 2 + 0], ti = hts[np * 2 + 1];
  const float* ea_h = ent_att + (size_t)(n * E_ + hi) * H_ * C_;
  const float* ea_t = ent_att + (size_t)(n * E_ + ti) * H_ * C_;
  const int t = threadIdx.x;           // 0..63
  float4 v[4];
  float local = 0.f;
#pragma unroll
  for (int q = 0; q < 4; ++q) {
    int c = t * 4 + 256 * q;
    float4 a = {0.f, 0.f, 0.f, 0.f};
#pragma unroll
    for (int h = 0; h < H_; ++h) {
      float4 x = *(const float4*)(ea_h + (size_t)h * C_ + c);
      float4 y = *(const float4*)(ea_t + (size_t)h * C_ + c);
      a.x += x.x * y.x; a.y += x.y * y.y; a.z += x.z * y.z; a.w += x.w * y.w;
    }
    a.x /= 12.f; a.y /= 12.f; a.z /= 12.f; a.w /= 12.f;
    v[q] = a;
    local += a.x + a.y + a.z + a.w;
  }
  float s = local;
#pragma unroll
  for (int m = 32; m > 0; m >>= 1) s += __shfl_xor(s, m);
  float S = s + 1e-5f;
#pragma unroll
  for (int q = 0; q < 4; ++q) {
    int c = t * 4 + 256 * q;
    float4 o;
    o.x = v[q].x / S; o.y = v[q].y / S; o.z = v[q].z / S; o.w = v[q].w / S;
    *(float4*)&ht[(size_t)np * C_ + c] = o;
  }
}

// ---------------------------------------------------------------- D: rs GEMM (round-4 form)
__global__ void k_rs(const float* __restrict__ ht, const float* __restrict__ seq,
                     float* __restrict__ rs) {
  const int pt0 = blockIdx.x * 16;     // 200 tiles
  const int n = pt0 / P_;
  const int ot = threadIdx.x & 63;
  const int jt = threadIdx.x >> 6;     // 0..3
  const int o0 = blockIdx.y * 256 + ot;
  __shared__ float hlds[16 * 66];
  float a32[4][4];
  double a64[4][4];
#pragma unroll
  for (int q = 0; q < 4; ++q)
#pragma unroll
    for (int i = 0; i < 4; ++i) { a32[q][i] = 0.f; a64[q][i] = 0.0; }
  const float* seqn = seq + (size_t)n * C_ * D_;
  for (int c0 = 0; c0 < C_; c0 += 64) {
    for (int l = threadIdx.x; l < 1024; l += 256) {
      int j = l >> 6, cc = l & 63;
      hlds[j * 66 + cc] = ht[(size_t)(pt0 + j) * C_ + c0 + cc];
    }
    __syncthreads();
#pragma unroll 4
    for (int cc = 0; cc < 64; ++cc) {
      float sv[4];
#pragma unroll
      for (int i = 0; i < 4; ++i) sv[i] = seqn[(size_t)(c0 + cc) * D_ + o0 + 64 * i];
#pragma unroll
      for (int q = 0; q < 4; ++q) {
        float w = hlds[(jt * 4 + q) * 66 + cc];
#pragma unroll
        for (int i = 0; i < 4; ++i) a32[q][i] += w * sv[i];
      }
    }
#pragma unroll
    for (int q = 0; q < 4; ++q)
#pragma unroll
      for (int i = 0; i < 4; ++i) { a64[q][i] += (double)a32[q][i]; a32[q][i] = 0.f; }
    __syncthreads();
  }
#pragma unroll
  for (int q = 0; q < 4; ++q) {
    int p = pt0 + jt * 4 + q;
#pragma unroll
    for (int i = 0; i < 4; ++i)
      rs[(size_t)p * D_ + o0 + 64 * i] = (float)a64[q][i];
  }
}

// ---------------------------------------------------------------- E: zh / zt (round-4 form)
__global__ void k_zht(const float* __restrict__ ent_emb, const float* __restrict__ rs,
                      const int* __restrict__ hts, const float* __restrict__ W,
                      const float* __restrict__ bias, float* __restrict__ out,
                      int which, int dbl_tanh) {
  const int pt0 = blockIdx.x * 16;
  const int n = pt0 / P_;
  const int ot = threadIdx.x & 63;
  const int jt = threadIdx.x >> 6;
  const int o0 = blockIdx.y * 256 + ot;
  __shared__ float xlds[16 * 66];
  __shared__ int sidx[16];
  if (threadIdx.x < 16) sidx[threadIdx.x] = hts[(pt0 + threadIdx.x) * 2 + which];
  float a32[4][4];
  double a64[4][4];
#pragma unroll
  for (int q = 0; q < 4; ++q)
#pragma unroll
    for (int i = 0; i < 4; ++i) { a32[q][i] = 0.f; a64[q][i] = 0.0; }
  __syncthreads();
  for (int k0 = 0; k0 < IN2_; k0 += 64) {
    for (int l = threadIdx.x; l < 1024; l += 256) {
      int j = l >> 6, q = l & 63;
      int kx = k0 + q;
      float val;
      if (kx < D_) val = ent_emb[(size_t)(n * E_ + sidx[j]) * D_ + kx];
      else         val = rs[(size_t)(pt0 + j) * D_ + (kx - D_)];
      xlds[j * 66 + q] = val;
    }
    __syncthreads();
#pragma unroll 4
    for (int q = 0; q < 64; ++q) {
      float wv[4];
#pragma unroll
      for (int i = 0; i < 4; ++i) wv[i] = W[(size_t)(k0 + q) * EMB_ + o0 + 64 * i];
#pragma unroll
      for (int j = 0; j < 4; ++j) {
        float x = xlds[(jt * 4 + j) * 66 + q];
#pragma unroll
        for (int i = 0; i < 4; ++i) a32[j][i] += x * wv[i];
      }
    }
#pragma unroll
    for (int j = 0; j < 4; ++j)
#pragma unroll
      for (int i = 0; i < 4; ++i) { a64[j][i] += (double)a32[j][i]; a32[j][i] = 0.f; }
    __syncthreads();
  }
#pragma unroll
  for (int j = 0; j < 4; ++j) {
    int p = pt0 + jt * 4 + j;
#pragma unroll
    for (int i = 0; i < 4; ++i) {
      int o = o0 + 64 * i;
      double z = a64[j][i] + (double)bias[o];
      z = tanh(z);
      if (dbl_tanh) z = tanh(z);
      out[(size_t)p * EMB_ + o] = (float)z;
    }
  }
}

// ---------------------------------------------------------------- F: logits partial (r 0..95)
// Round-4 skeleton (full 64x97 W slice per b, 2 barriers per b) + two changes:
//  (1) zt/zh tiles staged ONCE into LDS -> inner loop has no global loads;
//  (2) next-b W slice prefetched into regs right after the visibility barrier,
//      consumed by ds_write at the NEXT iteration -> L2 latency hides under
//      the ~8200-cycle compute of the current b.
// Summation order (c asc within b, b asc) bit-identical to rounds 4/5.
__global__ __launch_bounds__(128) void k_logits_part(
    const float* __restrict__ zh, const float* __restrict__ zt,
    const float* __restrict__ Wb, float* __restrict__ part) {
  const int bid = blockIdx.x;          // 0..1199
  const int s   = bid % 24;            // slab = k*2+bh  (XCD s%8 affinity)
  const int t   = bid / 24;            // p-tile 0..49
  const int k   = s >> 1, bh = s & 1;
  const int pt0 = t * 64;
  const int rt = threadIdx.x & 15;
  const int pg = threadIdx.x >> 4;     // 0..7 -> pairs pg*8+j
  const int kb0 = k * 64 + bh * 32;

  __shared__ float Wlin[64 * 97];      // 24832 B
  __shared__ float ztl[64][68];        // 17408 B (16B-aligned rows)
  __shared__ float zhl[64][36];        // 9216 B  -> total 51456 B, 3 blk/CU

  // ---- stage zt tile once: 64 pairs x 64 c
  {
    int p = threadIdx.x >> 1, half = threadIdx.x & 1;
    const float* src = zt + (size_t)(pt0 + p) * EMB_ + k * 64 + half * 32;
#pragma unroll
    for (int i = 0; i < 8; ++i)
      *(float4*)&ztl[p][half * 32 + i * 4] = *(const float4*)(src + i * 4);
  }
  // ---- stage zh tile once: 64 pairs x 32 b
  {
    int p = threadIdx.x >> 1, half = threadIdx.x & 1;
    const float* src = zh + (size_t)(pt0 + p) * EMB_ + kb0 + half * 16;
#pragma unroll
    for (int i = 0; i < 4; ++i)
      *(float4*)&zhl[p][half * 16 + i * 4] = *(const float4*)(src + i * 4);
  }

  // ---- W full-slice staging helpers (1552 float4 per slice)
  auto stage_regs = [&](int b, float4* wreg) {
    const float4* src = (const float4*)(Wb + (size_t)(kb0 + b) * 6208);
#pragma unroll
    for (int u = 0; u < 12; ++u)
      wreg[u] = src[threadIdx.x + 128 * u];
    if (threadIdx.x < 16) wreg[12] = src[1536 + threadIdx.x];
  };
  auto write_lds = [&](const float4* wreg) {
    float4* dst = (float4*)Wlin;
#pragma unroll
    for (int u = 0; u < 12; ++u)
      dst[threadIdx.x + 128 * u] = wreg[u];
    if (threadIdx.x < 16) dst[1536 + threadIdx.x] = wreg[12];
  };

  float4 wreg[13];
  stage_regs(0, wreg);                 // issue b=0 loads (overlaps zt/zh staging)

  float acc[8][6];
#pragma unroll
  for (int j = 0; j < 8; ++j)
#pragma unroll
    for (int i = 0; i < 6; ++i) acc[j][i] = 0.f;

  for (int b = 0; b < 32; ++b) {
    if (b > 0) __syncthreads();        // readers of slice b-1 done
    write_lds(wreg);                   // waits on the prefetch loads
    __syncthreads();                   // W slice (and, at b=0, zt/zh tiles) visible
    if (b < 31) stage_regs(b + 1, wreg);   // issue next-b loads, no wait

    float zhv[8];
#pragma unroll
    for (int j = 0; j < 8; ++j) zhv[j] = zhl[pg * 8 + j][b];

    for (int c0 = 0; c0 < 64; c0 += 4) {
      float4 pz[8];
#pragma unroll
      for (int j = 0; j < 8; ++j) {
        float4 z = *(const float4*)&ztl[pg * 8 + j][c0];
        pz[j].x = zhv[j] * z.x; pz[j].y = zhv[j] * z.y;
        pz[j].z = zhv[j] * z.z; pz[j].w = zhv[j] * z.w;
      }
#pragma unroll
      for (int cc = 0; cc < 4; ++cc) {
        const float* wr = &Wlin[(c0 + cc) * 97];
#pragma unroll
        for (int i = 0; i < 6; ++i) {
          float w = wr[rt + 16 * i];
#pragma unroll
          for (int j = 0; j < 8; ++j) {
            float pzc = (cc == 0) ? pz[j].x : (cc == 1) ? pz[j].y
                      : (cc == 2) ? pz[j].z : pz[j].w;
            acc[j][i] += pzc * w;
          }
        }
      }
    }
  }

  float* po = part + (size_t)s * NP_ * NREL_;
#pragma unroll
  for (int j = 0; j < 8; ++j) {
    int p = pt0 + pg * 8 + j;
#pragma unroll
    for (int i = 0; i < 6; ++i)
      po[(size_t)p * NREL_ + rt + 16 * i] = acc[j][i];
  }
}

// ---------------------------------------------------------------- F2: r=96 column
__global__ void k_r96(const float* __restrict__ zh, const float* __restrict__ zt,
                      const float* __restrict__ Wb, float* __restrict__ part) {
  const int pt0 = blockIdx.x * 64;
  const int k  = blockIdx.y;
  const int bh = blockIdx.z;
  const int p = pt0 + (threadIdx.x >> 1);
  const int ch = threadIdx.x & 1;
  const int kb0 = k * 64 + bh * 32;
  const float* zhr = zh + (size_t)p * EMB_ + kb0;
  const float* ztr = zt + (size_t)p * EMB_ + k * 64 + ch * 32;
  float acc = 0.f;
  for (int b = 0; b < 32; ++b) {
    float zhb = zhr[b];
    const float* w = Wb + (size_t)((kb0 + b) * 64 + ch * 32) * NREL_ + 96;
#pragma unroll 8
    for (int c = 0; c < 32; ++c)
      acc += zhb * ztr[c] * w[(size_t)c * NREL_];
  }
  acc += __shfl_xor(acc, 1);
  if (ch == 0)
    part[(size_t)(k * 2 + bh) * NP_ * NREL_ + (size_t)p * NREL_ + 96] = acc;
}

// ---------------------------------------------------------------- G: finalize
__global__ void k_final(const float* __restrict__ part, const float* __restrict__ bb,
                        float* __restrict__ out) {
  const int p = blockIdx.x;
  const int r = threadIdx.x;           // 128 threads
  __shared__ double th_s;
  __shared__ int cnt[128];
  double v = 0.0;
  if (r < NREL_) {
#pragma unroll
    for (int g = 0; g < NPART; ++g)
      v += (double)part[(size_t)g * NP_ * NREL_ + (size_t)p * NREL_ + r];
    v += (double)bb[r];
    out[(size_t)p * NREL_ + r] = (float)v;
  }
  if (r == 0) th_s = v;
  __syncthreads();
  int pred = (r >= 1 && r < NREL_ && v > th_s) ? 1 : 0;
  cnt[r] = pred;
  __syncthreads();
  for (int s = 64; s > 0; s >>= 1) {
    if (r < s) cnt[r] += cnt[r + s];
    __syncthreads();
  }
  if (r < NREL_) {
    float pv = (r == 0) ? ((cnt[0] == 0) ? 1.f : 0.f) : (float)pred;
    out[(size_t)NP_ * NREL_ + (size_t)p * NREL_ + r] = pv;
  }
}

extern "C" void kernel_launch(void* const* d_in, const int* in_sizes, int n_in,
                              void* d_out, int out_size, void* d_ws, size_t ws_size,
                              hipStream_t stream) {
  const float* seq  = (const float*)d_in[0];
  const float* att  = (const float*)d_in[1];
  const int*   mpos = (const int*)d_in[2];
  const int*   hts  = (const int*)d_in[3];
  const float* Wh   = (const float*)d_in[4];
  const float* bh   = (const float*)d_in[5];
  const float* Wt   = (const float*)d_in[6];
  const float* bt   = (const float*)d_in[7];
  const float* Wb   = (const float*)d_in[8];
  const float* bb   = (const float*)d_in[9];
  float* out = (float*)d_out;
  float* ws = (float*)d_ws;

  float* ent_emb = ws;                   // [0, 122880)
  float* ent_att = ws + 122880;          // dead after k_ht_att
  float* ht      = ws + 2088960;         // dead after k_rs
  float* rs      = ws + 5365760;         // dead after k_zht
  float* zh      = ws + 7823360;
  float* zt      = ws + 10280960;
  // part (24*3200*97 floats) aliases dead ent_att+ht+rs: [122880, 7572480)
  float* part    = ws + 122880;

  k_ent_emb<<<160, 256, 0, stream>>>(seq, mpos, ent_emb);
  k_ent_att<<<7680, 256, 0, stream>>>(att, mpos, ent_att);
  k_ht_att<<<3200, 64, 0, stream>>>(ent_att, hts, ht);
  k_rs<<<dim3(200, 3), 256, 0, stream>>>(ht, seq, rs);
  k_zht<<<dim3(200, 3), 256, 0, stream>>>(ent_emb, rs, hts, Wh, bh, zh, 0, 1);
  k_zht<<<dim3(200, 3), 256, 0, stream>>>(ent_emb, rs, hts, Wt, bt, zt, 1, 0);
  k_logits_part<<<1200, 128, 0, stream>>>(zh, zt, Wb, part);
  k_r96<<<dim3(50, 12, 2), 128, 0, stream>>>(zh, zt, Wb, part);
  k_final<<<3200, 128, 0, stream>>>(part, bb, out);
}

// Round 7
// 1340.369 us; speedup vs baseline: 1.4881x; 1.1356x over previous
//
#include <hip/hip_runtime.h>
#include <hip/hip_bf16.h>
#include <math.h>

#define N_DOC 4
#define C_    1024
#define D_    768
#define H_    12
#define E_    40
#define M_    3
#define P_    800
#define NP_   3200
#define EMB_  768
#define NREL_ 97
#define IN2_  1536   // 2*D
#define NPART 24     // 12 k-blocks x 2 b-halves

#define GLOAD_LDS16(g, l) \
  __builtin_amdgcn_global_load_lds( \
      (const __attribute__((address_space(1))) void*)(g), \
      (__attribute__((address_space(3))) void*)(l), 16, 0, 0)

// ---------------------------------------------------------------- A: ent_emb
__global__ void k_ent_emb(const float* __restrict__ seq, const int* __restrict__ mpos,
                          float* __restrict__ ent_emb) {
  int ne = blockIdx.x;                 // 0..159
  int n = ne / E_, e = ne % E_;
  int base = (n * E_ + e) * M_;
  int p0 = mpos[base + 0] + 1, p1 = mpos[base + 1] + 1, p2 = mpos[base + 2] + 1;
  const float* s0 = seq + ((size_t)n * C_ + p0) * D_;
  const float* s1 = seq + ((size_t)n * C_ + p1) * D_;
  const float* s2 = seq + ((size_t)n * C_ + p2) * D_;
  float* out = ent_emb + (size_t)ne * D_;
  for (int d = threadIdx.x; d < D_; d += blockDim.x) {
    double a = s0[d], b = s1[d], c = s2[d];
    double mx = fmax(a, fmax(b, c));
    double s = exp(a - mx) + exp(b - mx) + exp(c - mx);
    out[d] = (float)(mx + log(s));
  }
}

// ---------------------------------------------------------------- B: ent_att
__global__ void k_ent_att(const float* __restrict__ att, const int* __restrict__ mpos,
                          float* __restrict__ ent_att) {
  int idx = blockIdx.x * 256 + threadIdx.x;        // exactly N*E*H*C = 1966080
  int c = idx & (C_ - 1);
  int h = (idx >> 10) % H_;
  int rem = idx / (C_ * H_);
  int e = rem % E_;
  int n = rem / E_;
  int base = (n * E_ + e) * M_;
  float acc = 0.f;
#pragma unroll
  for (int m = 0; m < M_; ++m) {
    int p = mpos[base + m] + 1;
    acc += att[(((size_t)n * H_ + h) * C_ + p) * C_ + c];
  }
  ent_att[idx] = acc / 3.0f;
}

// ---------------------------------------------------------------- C: ht_att
__global__ void k_ht_att(const float* __restrict__ ent_att, const int* __restrict__ hts,
                         float* __restrict__ ht) {
  int np = blockIdx.x;                 // 0..3199
  int n = np / P_;
  int hi = hts[np * 2 + 0], ti = hts[np * 2 + 1];
  const float* ea_h = ent_att + (size_t)(n * E_ + hi) * H_ * C_;
  const float* ea_t = ent_att + (size_t)(n * E_ + ti) * H_ * C_;
  const int t = threadIdx.x;           // 0..63
  float4 v[4];
  float local = 0.f;
#pragma unroll
  for (int q = 0; q < 4; ++q) {
    int c = t * 4 + 256 * q;
    float4 a = {0.f, 0.f, 0.f, 0.f};
#pragma unroll
    for (int h = 0; h < H_; ++h) {
      float4 x = *(const float4*)(ea_h + (size_t)h * C_ + c);
      float4 y = *(const float4*)(ea_t + (size_t)h * C_ + c);
      a.x += x.x * y.x; a.y += x.y * y.y; a.z += x.z * y.z; a.w += x.w * y.w;
    }
    a.x /= 12.f; a.y /= 12.f; a.z /= 12.f; a.w /= 12.f;
    v[q] = a;
    local += a.x + a.y + a.z + a.w;
  }
  float s = local;
#pragma unroll
  for (int m = 32; m > 0; m >>= 1) s += __shfl_xor(s, m);
  float S = s + 1e-5f;
#pragma unroll
  for (int q = 0; q < 4; ++q) {
    int c = t * 4 + 256 * q;
    float4 o;
    o.x = v[q].x / S; o.y = v[q].y / S; o.z = v[q].z / S; o.w = v[q].w / S;
    *(float4*)&ht[(size_t)np * C_ + c] = o;
  }
}

// ---------------------------------------------------------------- D: rs GEMM
// Thread owns 4 CONSECUTIVE o (one float4 seq load per c) -> 1 load per 16 FMA.
// k-order per output unchanged -> rs bit-identical to prior rounds.
__global__ void k_rs(const float* __restrict__ ht, const float* __restrict__ seq,
                     float* __restrict__ rs) {
  const int pt0 = blockIdx.x * 16;     // 200 tiles
  const int n = pt0 / P_;
  const int ot = threadIdx.x & 63;
  const int jt = threadIdx.x >> 6;     // 0..3
  const int o4 = blockIdx.y * 256 + ot * 4;
  __shared__ float hlds[16 * 66];
  float4 a32[4];
  double a64[4][4];
#pragma unroll
  for (int q = 0; q < 4; ++q) {
    a32[q] = {0.f, 0.f, 0.f, 0.f};
#pragma unroll
    for (int i = 0; i < 4; ++i) a64[q][i] = 0.0;
  }
  const float* seqn = seq + (size_t)n * C_ * D_;
  for (int c0 = 0; c0 < C_; c0 += 64) {
    for (int l = threadIdx.x; l < 1024; l += 256) {
      int j = l >> 6, cc = l & 63;
      hlds[j * 66 + cc] = ht[(size_t)(pt0 + j) * C_ + c0 + cc];
    }
    __syncthreads();
#pragma unroll 4
    for (int cc = 0; cc < 64; ++cc) {
      float4 sv = *(const float4*)&seqn[(size_t)(c0 + cc) * D_ + o4];
#pragma unroll
      for (int q = 0; q < 4; ++q) {
        float w = hlds[(jt * 4 + q) * 66 + cc];
        a32[q].x += w * sv.x; a32[q].y += w * sv.y;
        a32[q].z += w * sv.z; a32[q].w += w * sv.w;
      }
    }
#pragma unroll
    for (int q = 0; q < 4; ++q) {
      a64[q][0] += (double)a32[q].x; a64[q][1] += (double)a32[q].y;
      a64[q][2] += (double)a32[q].z; a64[q][3] += (double)a32[q].w;
      a32[q] = {0.f, 0.f, 0.f, 0.f};
    }
    __syncthreads();
  }
#pragma unroll
  for (int q = 0; q < 4; ++q) {
    int p = pt0 + jt * 4 + q;
#pragma unroll
    for (int i = 0; i < 4; ++i)
      rs[(size_t)p * D_ + o4 + i] = (float)a64[q][i];
  }
}

// ---------------------------------------------------------------- E: zh / zt
// Same float4-over-o restructure; k-order unchanged -> zh/zt bit-identical.
__global__ void k_zht(const float* __restrict__ ent_emb, const float* __restrict__ rs,
                      const int* __restrict__ hts, const float* __restrict__ W,
                      const float* __restrict__ bias, float* __restrict__ out,
                      int which, int dbl_tanh) {
  const int pt0 = blockIdx.x * 16;
  const int n = pt0 / P_;
  const int ot = threadIdx.x & 63;
  const int jt = threadIdx.x >> 6;
  const int o4 = blockIdx.y * 256 + ot * 4;
  __shared__ float xlds[16 * 66];
  __shared__ int sidx[16];
  if (threadIdx.x < 16) sidx[threadIdx.x] = hts[(pt0 + threadIdx.x) * 2 + which];
  float4 a32[4];
  double a64[4][4];
#pragma unroll
  for (int q = 0; q < 4; ++q) {
    a32[q] = {0.f, 0.f, 0.f, 0.f};
#pragma unroll
    for (int i = 0; i < 4; ++i) a64[q][i] = 0.0;
  }
  __syncthreads();
  for (int k0 = 0; k0 < IN2_; k0 += 64) {
    for (int l = threadIdx.x; l < 1024; l += 256) {
      int j = l >> 6, q = l & 63;
      int kx = k0 + q;
      float val;
      if (kx < D_) val = ent_emb[(size_t)(n * E_ + sidx[j]) * D_ + kx];
      else         val = rs[(size_t)(pt0 + j) * D_ + (kx - D_)];
      xlds[j * 66 + q] = val;
    }
    __syncthreads();
#pragma unroll 4
    for (int q = 0; q < 64; ++q) {
      float4 wv = *(const float4*)&W[(size_t)(k0 + q) * EMB_ + o4];
#pragma unroll
      for (int j = 0; j < 4; ++j) {
        float x = xlds[(jt * 4 + j) * 66 + q];
        a32[j].x += x * wv.x; a32[j].y += x * wv.y;
        a32[j].z += x * wv.z; a32[j].w += x * wv.w;
      }
    }
#pragma unroll
    for (int j = 0; j < 4; ++j) {
      a64[j][0] += (double)a32[j].x; a64[j][1] += (double)a32[j].y;
      a64[j][2] += (double)a32[j].z; a64[j][3] += (double)a32[j].w;
      a32[j] = {0.f, 0.f, 0.f, 0.f};
    }
    __syncthreads();
  }
#pragma unroll
  for (int j = 0; j < 4; ++j) {
    int p = pt0 + jt * 4 + j;
#pragma unroll
    for (int i = 0; i < 4; ++i) {
      int o = o4 + i;
      double z = a64[j][i] + (double)bias[o];
      z = tanh(z);
      if (dbl_tanh) z = tanh(z);
      out[(size_t)p * EMB_ + o] = (float)z;
    }
  }
}

// ---------------------------------------------------------------- F: logits partial (all 97 r)
// Round-4 skeleton; W slice staged via async global_load_lds (width 16, no VGPR
// round-trip, no spill); zt/zh tiles LDS-resident; r=96 folded in (broadcast
// w6 read, any-lane-identical acc6, rt==0 stores). __syncthreads() drains
// vmcnt -> DMA completion guaranteed. Sum order (c asc, b asc) == rounds 4-6.
__global__ __launch_bounds__(128) void k_logits_part(
    const float* __restrict__ zh, const float* __restrict__ zt,
    const float* __restrict__ Wb, float* __restrict__ part) {
  const int bid = blockIdx.x;          // 0..1199
  const int s   = bid % 24;            // slab = k*2+bh  (XCD s%8 affinity)
  const int t   = bid / 24;            // p-tile 0..49
  const int k   = s >> 1, bh = s & 1;
  const int pt0 = t * 64;
  const int rt = threadIdx.x & 15;
  const int pg = threadIdx.x >> 4;     // 0..7 -> pairs pg*8+j
  const int kb0 = k * 64 + bh * 32;

  __shared__ float Wlin[64 * 97];      // 24832 B
  __shared__ float ztl[64][68];        // 17408 B
  __shared__ float zhl[64][36];        // 9216 B  -> 51456 B total, 3 blk/CU

  // ---- async-stage W slice for b (1552 float4: 12 full rounds + 16 tail)
  auto stage_w = [&](int b) {
    const float* src = Wb + (size_t)(kb0 + b) * 6208;
#pragma unroll
    for (int u = 0; u < 12; ++u)
      GLOAD_LDS16(src + (u * 128 + threadIdx.x) * 4,
                  Wlin + (u * 128 + threadIdx.x) * 4);
    if (threadIdx.x < 16)
      GLOAD_LDS16(src + (1536 + threadIdx.x) * 4,
                  Wlin + (1536 + threadIdx.x) * 4);
  };

  stage_w(0);                          // in flight during zt/zh staging

  // ---- stage zt tile once: 64 pairs x 64 c
  {
    int p = threadIdx.x >> 1, half = threadIdx.x & 1;
    const float* src = zt + (size_t)(pt0 + p) * EMB_ + k * 64 + half * 32;
#pragma unroll
    for (int i = 0; i < 8; ++i)
      *(float4*)&ztl[p][half * 32 + i * 4] = *(const float4*)(src + i * 4);
  }
  // ---- stage zh tile once: 64 pairs x 32 b
  {
    int p = threadIdx.x >> 1, half = threadIdx.x & 1;
    const float* src = zh + (size_t)(pt0 + p) * EMB_ + kb0 + half * 16;
#pragma unroll
    for (int i = 0; i < 4; ++i)
      *(float4*)&zhl[p][half * 16 + i * 4] = *(const float4*)(src + i * 4);
  }

  float acc[8][6];
  float acc6[8];
#pragma unroll
  for (int j = 0; j < 8; ++j) {
    acc6[j] = 0.f;
#pragma unroll
    for (int i = 0; i < 6; ++i) acc[j][i] = 0.f;
  }

  __syncthreads();                     // drains vmcnt: Wlin(b=0), ztl, zhl ready

  for (int b = 0; b < 32; ++b) {
    float zhv[8];
#pragma unroll
    for (int j = 0; j < 8; ++j) zhv[j] = zhl[pg * 8 + j][b];

    for (int c0 = 0; c0 < 64; c0 += 4) {
      float4 pz[8];
#pragma unroll
      for (int j = 0; j < 8; ++j) {
        float4 z = *(const float4*)&ztl[pg * 8 + j][c0];
        pz[j].x = zhv[j] * z.x; pz[j].y = zhv[j] * z.y;
        pz[j].z = zhv[j] * z.z; pz[j].w = zhv[j] * z.w;
      }
#pragma unroll
      for (int cc = 0; cc < 4; ++cc) {
        const float* wr = &Wlin[(c0 + cc) * 97];
        float w6 = wr[96];             // broadcast read, same across lanes
#pragma unroll
        for (int i = 0; i < 6; ++i) {
          float w = wr[rt + 16 * i];
#pragma unroll
          for (int j = 0; j < 8; ++j) {
            float pzc = (cc == 0) ? pz[j].x : (cc == 1) ? pz[j].y
                      : (cc == 2) ? pz[j].z : pz[j].w;
            acc[j][i] += pzc * w;
          }
        }
#pragma unroll
        for (int j = 0; j < 8; ++j) {
          float pzc = (cc == 0) ? pz[j].x : (cc == 1) ? pz[j].y
                    : (cc == 2) ? pz[j].z : pz[j].w;
          acc6[j] += pzc * w6;
        }
      }
    }
    if (b < 31) {
      __syncthreads();                 // all readers of Wlin(b) done
      stage_w(b + 1);
      __syncthreads();                 // drains vmcnt: Wlin(b+1) ready
    }
  }

  float* po = part + (size_t)s * NP_ * NREL_;
#pragma unroll
  for (int j = 0; j < 8; ++j) {
    int p = pt0 + pg * 8 + j;
#pragma unroll
    for (int i = 0; i < 6; ++i)
      po[(size_t)p * NREL_ + rt + 16 * i] = acc[j][i];
    if (rt == 0) po[(size_t)p * NREL_ + 96] = acc6[j];
  }
}

// ---------------------------------------------------------------- G: finalize
__global__ void k_final(const float* __restrict__ part, const float* __restrict__ bb,
                        float* __restrict__ out) {
  const int p = blockIdx.x;
  const int r = threadIdx.x;           // 128 threads
  __shared__ double th_s;
  __shared__ int cnt[128];
  double v = 0.0;
  if (r < NREL_) {
#pragma unroll
    for (int g = 0; g < NPART; ++g)
      v += (double)part[(size_t)g * NP_ * NREL_ + (size_t)p * NREL_ + r];
    v += (double)bb[r];
    out[(size_t)p * NREL_ + r] = (float)v;
  }
  if (r == 0) th_s = v;
  __syncthreads();
  int pred = (r >= 1 && r < NREL_ && v > th_s) ? 1 : 0;
  cnt[r] = pred;
  __syncthreads();
  for (int s = 64; s > 0; s >>= 1) {
    if (r < s) cnt[r] += cnt[r + s];
    __syncthreads();
  }
  if (r < NREL_) {
    float pv = (r == 0) ? ((cnt[0] == 0) ? 1.f : 0.f) : (float)pred;
    out[(size_t)NP_ * NREL_ + (size_t)p * NREL_ + r] = pv;
  }
}

extern "C" void kernel_launch(void* const* d_in, const int* in_sizes, int n_in,
                              void* d_out, int out_size, void* d_ws, size_t ws_size,
                              hipStream_t stream) {
  const float* seq  = (const float*)d_in[0];
  const float* att  = (const float*)d_in[1];
  const int*   mpos = (const int*)d_in[2];
  const int*   hts  = (const int*)d_in[3];
  const float* Wh   = (const float*)d_in[4];
  const float* bh   = (const float*)d_in[5];
  const float* Wt   = (const float*)d_in[6];
  const float* bt   = (const float*)d_in[7];
  const float* Wb   = (const float*)d_in[8];
  const float* bb   = (const float*)d_in[9];
  float* out = (float*)d_out;
  float* ws = (float*)d_ws;

  float* ent_emb = ws;                   // [0, 122880)
  float* ent_att = ws + 122880;          // dead after k_ht_att
  float* ht      = ws + 2088960;         // dead after k_rs
  float* rs      = ws + 5365760;         // dead after k_zht
  float* zh      = ws + 7823360;
  float* zt      = ws + 10280960;
  // part (24*3200*97 floats) aliases dead ent_att+ht+rs: [122880, 7572480)
  float* part    = ws + 122880;

  k_ent_emb<<<160, 256, 0, stream>>>(seq, mpos, ent_emb);
  k_ent_att<<<7680, 256, 0, stream>>>(att, mpos, ent_att);
  k_ht_att<<<3200, 64, 0, stream>>>(ent_att, hts, ht);
  k_rs<<<dim3(200, 3), 256, 0, stream>>>(ht, seq, rs);
  k_zht<<<dim3(200, 3), 256, 0, stream>>>(ent_emb, rs, hts, Wh, bh, zh, 0, 1);
  k_zht<<<dim3(200, 3), 256, 0, stream>>>(ent_emb, rs, hts, Wt, bt, zt, 1, 0);
  k_logits_part<<<1200, 128, 0, stream>>>(zh, zt, Wb, part);
  k_final<<<3200, 128, 0, stream>>>(part, bb, out);
}

// Round 9
// 1230.100 us; speedup vs baseline: 1.6215x; 1.0896x over previous
//
#include <hip/hip_runtime.h>
#include <hip/hip_bf16.h>
#include <math.h>

#define N_DOC 4
#define C_    1024
#define D_    768
#define H_    12
#define E_    40
#define M_    3
#define P_    800
#define NP_   3200
#define EMB_  768
#define NREL_ 97
#define IN2_  1536   // 2*D
#define NPART 24     // 12 k-blocks x 2 b-halves

#define GLOAD_LDS16(g, l) \
  __builtin_amdgcn_global_load_lds( \
      (const __attribute__((address_space(1))) void*)(g), \
      (__attribute__((address_space(3))) void*)(l), 16, 0, 0)

typedef float f32x2 __attribute__((ext_vector_type(2)));

// Single-instruction wrapper: d = a*b + c (packed 2xfp32). Inputs/outputs may
// alias freely (one VALU instr) -- no multi-instr asm hazards.
static __device__ __forceinline__ f32x2 pk_fma(f32x2 a, f32x2 b, f32x2 c) {
  f32x2 d;
  asm("v_pk_fma_f32 %0, %1, %2, %3" : "=v"(d) : "v"(a), "v"(b), "v"(c));
  return d;
}

// ---------------------------------------------------------------- A: ent_emb
__global__ void k_ent_emb(const float* __restrict__ seq, const int* __restrict__ mpos,
                          float* __restrict__ ent_emb) {
  int ne = blockIdx.x;                 // 0..159
  int n = ne / E_, e = ne % E_;
  int base = (n * E_ + e) * M_;
  int p0 = mpos[base + 0] + 1, p1 = mpos[base + 1] + 1, p2 = mpos[base + 2] + 1;
  const float* s0 = seq + ((size_t)n * C_ + p0) * D_;
  const float* s1 = seq + ((size_t)n * C_ + p1) * D_;
  const float* s2 = seq + ((size_t)n * C_ + p2) * D_;
  float* out = ent_emb + (size_t)ne * D_;
  for (int d = threadIdx.x; d < D_; d += blockDim.x) {
    double a = s0[d], b = s1[d], c = s2[d];
    double mx = fmax(a, fmax(b, c));
    double s = exp(a - mx) + exp(b - mx) + exp(c - mx);
    out[d] = (float)(mx + log(s));
  }
}

// ---------------------------------------------------------------- B: ent_att
__global__ void k_ent_att(const float* __restrict__ att, const int* __restrict__ mpos,
                          float* __restrict__ ent_att) {
  int idx = blockIdx.x * 256 + threadIdx.x;        // exactly N*E*H*C = 1966080
  int c = idx & (C_ - 1);
  int h = (idx >> 10) % H_;
  int rem = idx / (C_ * H_);
  int e = rem % E_;
  int n = rem / E_;
  int base = (n * E_ + e) * M_;
  float acc = 0.f;
#pragma unroll
  for (int m = 0; m < M_; ++m) {
    int p = mpos[base + m] + 1;
    acc += att[(((size_t)n * H_ + h) * C_ + p) * C_ + c];
  }
  ent_att[idx] = acc / 3.0f;
}

// ---------------------------------------------------------------- C: ht_att
__global__ void k_ht_att(const float* __restrict__ ent_att, const int* __restrict__ hts,
                         float* __restrict__ ht) {
  int np = blockIdx.x;                 // 0..3199
  int n = np / P_;
  int hi = hts[np * 2 + 0], ti = hts[np * 2 + 1];
  const float* ea_h = ent_att + (size_t)(n * E_ + hi) * H_ * C_;
  const float* ea_t = ent_att + (size_t)(n * E_ + ti) * H_ * C_;
  const int t = threadIdx.x;           // 0..63
  float4 v[4];
  float local = 0.f;
#pragma unroll
  for (int q = 0; q < 4; ++q) {
    int c = t * 4 + 256 * q;
    float4 a = {0.f, 0.f, 0.f, 0.f};
#pragma unroll
    for (int h = 0; h < H_; ++h) {
      float4 x = *(const float4*)(ea_h + (size_t)h * C_ + c);
      float4 y = *(const float4*)(ea_t + (size_t)h * C_ + c);
      a.x += x.x * y.x; a.y += x.y * y.y; a.z += x.z * y.z; a.w += x.w * y.w;
    }
    a.x /= 12.f; a.y /= 12.f; a.z /= 12.f; a.w /= 12.f;
    v[q] = a;
    local += a.x + a.y + a.z + a.w;
  }
  float s = local;
#pragma unroll
  for (int m = 32; m > 0; m >>= 1) s += __shfl_xor(s, m);
  float S = s + 1e-5f;
#pragma unroll
  for (int q = 0; q < 4; ++q) {
    int c = t * 4 + 256 * q;
    float4 o;
    o.x = v[q].x / S; o.y = v[q].y / S; o.z = v[q].z / S; o.w = v[q].w / S;
    *(float4*)&ht[(size_t)np * C_ + c] = o;
  }
}

// ---------------------------------------------------------------- D: rs GEMM (R7 form)
__global__ void k_rs(const float* __restrict__ ht, const float* __restrict__ seq,
                     float* __restrict__ rs) {
  const int pt0 = blockIdx.x * 16;     // 200 tiles
  const int n = pt0 / P_;
  const int ot = threadIdx.x & 63;
  const int jt = threadIdx.x >> 6;     // 0..3
  const int o4 = blockIdx.y * 256 + ot * 4;
  __shared__ float hlds[16 * 66];
  float4 a32[4];
  double a64[4][4];
#pragma unroll
  for (int q = 0; q < 4; ++q) {
    a32[q] = {0.f, 0.f, 0.f, 0.f};
#pragma unroll
    for (int i = 0; i < 4; ++i) a64[q][i] = 0.0;
  }
  const float* seqn = seq + (size_t)n * C_ * D_;
  for (int c0 = 0; c0 < C_; c0 += 64) {
    for (int l = threadIdx.x; l < 1024; l += 256) {
      int j = l >> 6, cc = l & 63;
      hlds[j * 66 + cc] = ht[(size_t)(pt0 + j) * C_ + c0 + cc];
    }
    __syncthreads();
#pragma unroll 4
    for (int cc = 0; cc < 64; ++cc) {
      float4 sv = *(const float4*)&seqn[(size_t)(c0 + cc) * D_ + o4];
#pragma unroll
      for (int q = 0; q < 4; ++q) {
        float w = hlds[(jt * 4 + q) * 66 + cc];
        a32[q].x += w * sv.x; a32[q].y += w * sv.y;
        a32[q].z += w * sv.z; a32[q].w += w * sv.w;
      }
    }
#pragma unroll
    for (int q = 0; q < 4; ++q) {
      a64[q][0] += (double)a32[q].x; a64[q][1] += (double)a32[q].y;
      a64[q][2] += (double)a32[q].z; a64[q][3] += (double)a32[q].w;
      a32[q] = {0.f, 0.f, 0.f, 0.f};
    }
    __syncthreads();
  }
#pragma unroll
  for (int q = 0; q < 4; ++q) {
    int p = pt0 + jt * 4 + q;
#pragma unroll
    for (int i = 0; i < 4; ++i)
      rs[(size_t)p * D_ + o4 + i] = (float)a64[q][i];
  }
}

// ---------------------------------------------------------------- E: zh / zt (R7 form)
__global__ void k_zht(const float* __restrict__ ent_emb, const float* __restrict__ rs,
                      const int* __restrict__ hts, const float* __restrict__ W,
                      const float* __restrict__ bias, float* __restrict__ out,
                      int which, int dbl_tanh) {
  const int pt0 = blockIdx.x * 16;
  const int n = pt0 / P_;
  const int ot = threadIdx.x & 63;
  const int jt = threadIdx.x >> 6;
  const int o4 = blockIdx.y * 256 + ot * 4;
  __shared__ float xlds[16 * 66];
  __shared__ int sidx[16];
  if (threadIdx.x < 16) sidx[threadIdx.x] = hts[(pt0 + threadIdx.x) * 2 + which];
  float4 a32[4];
  double a64[4][4];
#pragma unroll
  for (int q = 0; q < 4; ++q) {
    a32[q] = {0.f, 0.f, 0.f, 0.f};
#pragma unroll
    for (int i = 0; i < 4; ++i) a64[q][i] = 0.0;
  }
  __syncthreads();
  for (int k0 = 0; k0 < IN2_; k0 += 64) {
    for (int l = threadIdx.x; l < 1024; l += 256) {
      int j = l >> 6, q = l & 63;
      int kx = k0 + q;
      float val;
      if (kx < D_) val = ent_emb[(size_t)(n * E_ + sidx[j]) * D_ + kx];
      else         val = rs[(size_t)(pt0 + j) * D_ + (kx - D_)];
      xlds[j * 66 + q] = val;
    }
    __syncthreads();
#pragma unroll 4
    for (int q = 0; q < 64; ++q) {
      float4 wv = *(const float4*)&W[(size_t)(k0 + q) * EMB_ + o4];
#pragma unroll
      for (int j = 0; j < 4; ++j) {
        float x = xlds[(jt * 4 + j) * 66 + q];
        a32[j].x += x * wv.x; a32[j].y += x * wv.y;
        a32[j].z += x * wv.z; a32[j].w += x * wv.w;
      }
    }
#pragma unroll
    for (int j = 0; j < 4; ++j) {
      a64[j][0] += (double)a32[j].x; a64[j][1] += (double)a32[j].y;
      a64[j][2] += (double)a32[j].z; a64[j][3] += (double)a32[j].w;
      a32[j] = {0.f, 0.f, 0.f, 0.f};
    }
    __syncthreads();
  }
#pragma unroll
  for (int j = 0; j < 4; ++j) {
    int p = pt0 + jt * 4 + j;
#pragma unroll
    for (int i = 0; i < 4; ++i) {
      int o = o4 + i;
      double z = a64[j][i] + (double)bias[o];
      z = tanh(z);
      if (dbl_tanh) z = tanh(z);
      out[(size_t)p * EMB_ + o] = (float)z;
    }
  }
}

// ---------------------------------------------------------------- F: logits partial (all 97 r)
// R4/R7 skeleton: Wlin-only LDS (24.8 KB -> 6 blk/CU), global_load_lds staging,
// zt/zh from global (16-lane broadcast L1 hits). Compute uses v_pk_fma_f32
// paired over j: acc2[jp][i].x/.y are the j=2jp / j=2jp+1 accumulators, each
// summed in the exact R4-R7 order (c asc within b, b asc) -> partials
// bit-identical to the passing rounds. W reads are COMPILER-generated scalar
// LDS broadcasts (no inline-asm reads -- R8's aliasing hazard eliminated);
// the {w,w} pair is an explicit 1-mov dup.
__global__ __launch_bounds__(128) void k_logits_part(
    const float* __restrict__ zh, const float* __restrict__ zt,
    const float* __restrict__ Wb, float* __restrict__ part) {
  const int bid = blockIdx.x;          // 0..1199
  const int s   = bid % 24;            // slab = k*2+bh  (XCD s%8 affinity)
  const int t   = bid / 24;            // p-tile 0..49
  const int k   = s >> 1, bh = s & 1;
  const int pt0 = t * 64;
  const int rt = threadIdx.x & 15;
  const int pg = threadIdx.x >> 4;     // 0..7 -> pairs pg*8+j
  const int kb0 = k * 64 + bh * 32;

  __shared__ float Wlin[64 * 97];      // 24832 B only -> 6 blk/CU LDS cap

  auto stage_w = [&](int b) {
    const float* src = Wb + (size_t)(kb0 + b) * 6208;
#pragma unroll
    for (int u = 0; u < 12; ++u)
      GLOAD_LDS16(src + (u * 128 + threadIdx.x) * 4,
                  Wlin + (u * 128 + threadIdx.x) * 4);
    if (threadIdx.x < 16)
      GLOAD_LDS16(src + (1536 + threadIdx.x) * 4,
                  Wlin + (1536 + threadIdx.x) * 4);
  };

  stage_w(0);

  f32x2 acc2[4][6];                    // [j-pair][r-slot]
  f32x2 acc6[4];                       // [j-pair], r = 96
#pragma unroll
  for (int jp = 0; jp < 4; ++jp) {
    acc6[jp] = (f32x2){0.f, 0.f};
#pragma unroll
    for (int i = 0; i < 6; ++i) acc2[jp][i] = (f32x2){0.f, 0.f};
  }

  const float* ztb  = zt + (size_t)(pt0 + pg * 8) * EMB_ + k * 64;
  const float* zh_g = zh + (size_t)(pt0 + pg * 8) * EMB_ + kb0;

  __syncthreads();                     // drains vmcnt: Wlin(b=0) ready

  for (int b = 0; b < 32; ++b) {
    float zhv[8];
#pragma unroll
    for (int j = 0; j < 8; ++j) zhv[j] = zh_g[(size_t)j * EMB_ + b];

    for (int c0 = 0; c0 < 64; c0 += 4) {
      float4 ztv[8];
#pragma unroll
      for (int j = 0; j < 8; ++j)
        ztv[j] = *(const float4*)(ztb + (size_t)j * EMB_ + c0);
      // pz[jp][cc] = { zh[2jp]*zt[2jp][c0+cc], zh[2jp+1]*zt[2jp+1][c0+cc] }
      f32x2 pz[4][4];
#pragma unroll
      for (int jp = 0; jp < 4; ++jp) {
        pz[jp][0].x = zhv[2*jp] * ztv[2*jp].x;   pz[jp][0].y = zhv[2*jp+1] * ztv[2*jp+1].x;
        pz[jp][1].x = zhv[2*jp] * ztv[2*jp].y;   pz[jp][1].y = zhv[2*jp+1] * ztv[2*jp+1].y;
        pz[jp][2].x = zhv[2*jp] * ztv[2*jp].z;   pz[jp][2].y = zhv[2*jp+1] * ztv[2*jp+1].z;
        pz[jp][3].x = zhv[2*jp] * ztv[2*jp].w;   pz[jp][3].y = zhv[2*jp+1] * ztv[2*jp+1].w;
      }
#pragma unroll
      for (int cc = 0; cc < 4; ++cc) {
        const float* wr = &Wlin[(c0 + cc) * 97];
        f32x2 wws[6];
#pragma unroll
        for (int i = 0; i < 6; ++i) {
          float w = wr[rt + 16 * i];           // compiler ds_read_b32, broadcast
          wws[i] = (f32x2){w, w};
        }
        float w6 = wr[96];
        f32x2 w6p = (f32x2){w6, w6};
#pragma unroll
        for (int jp = 0; jp < 4; ++jp) {
          acc2[jp][0] = pk_fma(pz[jp][cc], wws[0], acc2[jp][0]);
          acc2[jp][1] = pk_fma(pz[jp][cc], wws[1], acc2[jp][1]);
          acc2[jp][2] = pk_fma(pz[jp][cc], wws[2], acc2[jp][2]);
          acc2[jp][3] = pk_fma(pz[jp][cc], wws[3], acc2[jp][3]);
          acc2[jp][4] = pk_fma(pz[jp][cc], wws[4], acc2[jp][4]);
          acc2[jp][5] = pk_fma(pz[jp][cc], wws[5], acc2[jp][5]);
          acc6[jp]    = pk_fma(pz[jp][cc], w6p,    acc6[jp]);
        }
      }
    }
    if (b < 31) {
      __syncthreads();                 // all readers of Wlin(b) done
      stage_w(b + 1);
      __syncthreads();                 // drains vmcnt: Wlin(b+1) ready
    }
  }

  float* po = part + (size_t)s * NP_ * NREL_;
#pragma unroll
  for (int jp = 0; jp < 4; ++jp) {
    int p0 = pt0 + pg * 8 + 2 * jp;
#pragma unroll
    for (int i = 0; i < 6; ++i) {
      po[(size_t)p0 * NREL_ + rt + 16 * i]       = acc2[jp][i].x;
      po[(size_t)(p0 + 1) * NREL_ + rt + 16 * i] = acc2[jp][i].y;
    }
    if (rt == 0) {
      po[(size_t)p0 * NREL_ + 96]       = acc6[jp].x;
      po[(size_t)(p0 + 1) * NREL_ + 96] = acc6[jp].y;
    }
  }
}

// ---------------------------------------------------------------- G: finalize
__global__ void k_final(const float* __restrict__ part, const float* __restrict__ bb,
                        float* __restrict__ out) {
  const int p = blockIdx.x;
  const int r = threadIdx.x;           // 128 threads
  __shared__ double th_s;
  __shared__ int cnt[128];
  double v = 0.0;
  if (r < NREL_) {
#pragma unroll
    for (int g = 0; g < NPART; ++g)
      v += (double)part[(size_t)g * NP_ * NREL_ + (size_t)p * NREL_ + r];
    v += (double)bb[r];
    out[(size_t)p * NREL_ + r] = (float)v;
  }
  if (r == 0) th_s = v;
  __syncthreads();
  int pred = (r >= 1 && r < NREL_ && v > th_s) ? 1 : 0;
  cnt[r] = pred;
  __syncthreads();
  for (int s = 64; s > 0; s >>= 1) {
    if (r < s) cnt[r] += cnt[r + s];
    __syncthreads();
  }
  if (r < NREL_) {
    float pv = (r == 0) ? ((cnt[0] == 0) ? 1.f : 0.f) : (float)pred;
    out[(size_t)NP_ * NREL_ + (size_t)p * NREL_ + r] = pv;
  }
}

extern "C" void kernel_launch(void* const* d_in, const int* in_sizes, int n_in,
                              void* d_out, int out_size, void* d_ws, size_t ws_size,
                              hipStream_t stream) {
  const float* seq  = (const float*)d_in[0];
  const float* att  = (const float*)d_in[1];
  const int*   mpos = (const int*)d_in[2];
  const int*   hts  = (const int*)d_in[3];
  const float* Wh   = (const float*)d_in[4];
  const float* bh   = (const float*)d_in[5];
  const float* Wt   = (const float*)d_in[6];
  const float* bt   = (const float*)d_in[7];
  const float* Wb   = (const float*)d_in[8];
  const float* bb   = (const float*)d_in[9];
  float* out = (float*)d_out;
  float* ws = (float*)d_ws;

  float* ent_emb = ws;                   // [0, 122880)
  float* ent_att = ws + 122880;          // dead after k_ht_att
  float* ht      = ws + 2088960;         // dead after k_rs
  float* rs      = ws + 5365760;         // dead after k_zht
  float* zh      = ws + 7823360;
  float* zt      = ws + 10280960;
  // part (24*3200*97 floats) aliases dead ent_att+ht+rs: [122880, 7572480)
  float* part    = ws + 122880;

  k_ent_emb<<<160, 256, 0, stream>>>(seq, mpos, ent_emb);
  k_ent_att<<<7680, 256, 0, stream>>>(att, mpos, ent_att);
  k_ht_att<<<3200, 64, 0, stream>>>(ent_att, hts, ht);
  k_rs<<<dim3(200, 3), 256, 0, stream>>>(ht, seq, rs);
  k_zht<<<dim3(200, 3), 256, 0, stream>>>(ent_emb, rs, hts, Wh, bh, zh, 0, 1);
  k_zht<<<dim3(200, 3), 256, 0, stream>>>(ent_emb, rs, hts, Wt, bt, zt, 1, 0);
  k_logits_part<<<1200, 128, 0, stream>>>(zh, zt, Wb, part);
  k_final<<<3200, 128, 0, stream>>>(part, bb, out);
}

// Round 10
// 1141.462 us; speedup vs baseline: 1.7474x; 1.0777x over previous
//
#include <hip/hip_runtime.h>
#include <hip/hip_bf16.h>
#include <math.h>

#define N_DOC 4
#define C_    1024
#define D_    768
#define H_    12
#define E_    40
#define M_    3
#define P_    800
#define NP_   3200
#define EMB_  768
#define NREL_ 97
#define IN2_  1536   // 2*D
#define NPART 24     // 12 k-blocks x 2 b-halves

#define GLOAD_LDS16(g, l) \
  __builtin_amdgcn_global_load_lds( \
      (const __attribute__((address_space(1))) void*)(g), \
      (__attribute__((address_space(3))) void*)(l), 16, 0, 0)

// ---------------------------------------------------------------- A: ent_emb
__global__ void k_ent_emb(const float* __restrict__ seq, const int* __restrict__ mpos,
                          float* __restrict__ ent_emb) {
  int ne = blockIdx.x;                 // 0..159
  int n = ne / E_, e = ne % E_;
  int base = (n * E_ + e) * M_;
  int p0 = mpos[base + 0] + 1, p1 = mpos[base + 1] + 1, p2 = mpos[base + 2] + 1;
  const float* s0 = seq + ((size_t)n * C_ + p0) * D_;
  const float* s1 = seq + ((size_t)n * C_ + p1) * D_;
  const float* s2 = seq + ((size_t)n * C_ + p2) * D_;
  float* out = ent_emb + (size_t)ne * D_;
  for (int d = threadIdx.x; d < D_; d += blockDim.x) {
    double a = s0[d], b = s1[d], c = s2[d];
    double mx = fmax(a, fmax(b, c));
    double s = exp(a - mx) + exp(b - mx) + exp(c - mx);
    out[d] = (float)(mx + log(s));
  }
}

// ---------------------------------------------------------------- B: ent_att
__global__ void k_ent_att(const float* __restrict__ att, const int* __restrict__ mpos,
                          float* __restrict__ ent_att) {
  int idx = blockIdx.x * 256 + threadIdx.x;        // exactly N*E*H*C = 1966080
  int c = idx & (C_ - 1);
  int h = (idx >> 10) % H_;
  int rem = idx / (C_ * H_);
  int e = rem % E_;
  int n = rem / E_;
  int base = (n * E_ + e) * M_;
  float acc = 0.f;
#pragma unroll
  for (int m = 0; m < M_; ++m) {
    int p = mpos[base + m] + 1;
    acc += att[(((size_t)n * H_ + h) * C_ + p) * C_ + c];
  }
  ent_att[idx] = acc / 3.0f;
}

// ---------------------------------------------------------------- C: ht_att
__global__ void k_ht_att(const float* __restrict__ ent_att, const int* __restrict__ hts,
                         float* __restrict__ ht) {
  int np = blockIdx.x;                 // 0..3199
  int n = np / P_;
  int hi = hts[np * 2 + 0], ti = hts[np * 2 + 1];
  const float* ea_h = ent_att + (size_t)(n * E_ + hi) * H_ * C_;
  const float* ea_t = ent_att + (size_t)(n * E_ + ti) * H_ * C_;
  const int t = threadIdx.x;           // 0..63
  float4 v[4];
  float local = 0.f;
#pragma unroll
  for (int q = 0; q < 4; ++q) {
    int c = t * 4 + 256 * q;
    float4 a = {0.f, 0.f, 0.f, 0.f};
#pragma unroll
    for (int h = 0; h < H_; ++h) {
      float4 x = *(const float4*)(ea_h + (size_t)h * C_ + c);
      float4 y = *(const float4*)(ea_t + (size_t)h * C_ + c);
      a.x += x.x * y.x; a.y += x.y * y.y; a.z += x.z * y.z; a.w += x.w * y.w;
    }
    a.x /= 12.f; a.y /= 12.f; a.z /= 12.f; a.w /= 12.f;
    v[q] = a;
    local += a.x + a.y + a.z + a.w;
  }
  float s = local;
#pragma unroll
  for (int m = 32; m > 0; m >>= 1) s += __shfl_xor(s, m);
  float S = s + 1e-5f;
#pragma unroll
  for (int q = 0; q < 4; ++q) {
    int c = t * 4 + 256 * q;
    float4 o;
    o.x = v[q].x / S; o.y = v[q].y / S; o.z = v[q].z / S; o.w = v[q].w / S;
    *(float4*)&ht[(size_t)np * C_ + c] = o;
  }
}

// ---------------------------------------------------------------- D: rs GEMM
__global__ void k_rs(const float* __restrict__ ht, const float* __restrict__ seq,
                     float* __restrict__ rs) {
  const int pt0 = blockIdx.x * 16;     // 200 tiles
  const int n = pt0 / P_;
  const int ot = threadIdx.x & 63;
  const int jt = threadIdx.x >> 6;     // 0..3
  const int o4 = blockIdx.y * 256 + ot * 4;
  __shared__ float hlds[16 * 66];
  float4 a32[4];
  double a64[4][4];
#pragma unroll
  for (int q = 0; q < 4; ++q) {
    a32[q] = {0.f, 0.f, 0.f, 0.f};
#pragma unroll
    for (int i = 0; i < 4; ++i) a64[q][i] = 0.0;
  }
  const float* seqn = seq + (size_t)n * C_ * D_;
  for (int c0 = 0; c0 < C_; c0 += 64) {
    for (int l = threadIdx.x; l < 1024; l += 256) {
      int j = l >> 6, cc = l & 63;
      hlds[j * 66 + cc] = ht[(size_t)(pt0 + j) * C_ + c0 + cc];
    }
    __syncthreads();
#pragma unroll 4
    for (int cc = 0; cc < 64; ++cc) {
      float4 sv = *(const float4*)&seqn[(size_t)(c0 + cc) * D_ + o4];
#pragma unroll
      for (int q = 0; q < 4; ++q) {
        float w = hlds[(jt * 4 + q) * 66 + cc];
        a32[q].x += w * sv.x; a32[q].y += w * sv.y;
        a32[q].z += w * sv.z; a32[q].w += w * sv.w;
      }
    }
#pragma unroll
    for (int q = 0; q < 4; ++q) {
      a64[q][0] += (double)a32[q].x; a64[q][1] += (double)a32[q].y;
      a64[q][2] += (double)a32[q].z; a64[q][3] += (double)a32[q].w;
      a32[q] = {0.f, 0.f, 0.f, 0.f};
    }
    __syncthreads();
  }
#pragma unroll
  for (int q = 0; q < 4; ++q) {
    int p = pt0 + jt * 4 + q;
#pragma unroll
    for (int i = 0; i < 4; ++i)
      rs[(size_t)p * D_ + o4 + i] = (float)a64[q][i];
  }
}

// ---------------------------------------------------------------- E: zh / zt
__global__ void k_zht(const float* __restrict__ ent_emb, const float* __restrict__ rs,
                      const int* __restrict__ hts, const float* __restrict__ W,
                      const float* __restrict__ bias, float* __restrict__ out,
                      int which, int dbl_tanh) {
  const int pt0 = blockIdx.x * 16;
  const int n = pt0 / P_;
  const int ot = threadIdx.x & 63;
  const int jt = threadIdx.x >> 6;
  const int o4 = blockIdx.y * 256 + ot * 4;
  __shared__ float xlds[16 * 66];
  __shared__ int sidx[16];
  if (threadIdx.x < 16) sidx[threadIdx.x] = hts[(pt0 + threadIdx.x) * 2 + which];
  float4 a32[4];
  double a64[4][4];
#pragma unroll
  for (int q = 0; q < 4; ++q) {
    a32[q] = {0.f, 0.f, 0.f, 0.f};
#pragma unroll
    for (int i = 0; i < 4; ++i) a64[q][i] = 0.0;
  }
  __syncthreads();
  for (int k0 = 0; k0 < IN2_; k0 += 64) {
    for (int l = threadIdx.x; l < 1024; l += 256) {
      int j = l >> 6, q = l & 63;
      int kx = k0 + q;
      float val;
      if (kx < D_) val = ent_emb[(size_t)(n * E_ + sidx[j]) * D_ + kx];
      else         val = rs[(size_t)(pt0 + j) * D_ + (kx - D_)];
      xlds[j * 66 + q] = val;
    }
    __syncthreads();
#pragma unroll 4
    for (int q = 0; q < 64; ++q) {
      float4 wv = *(const float4*)&W[(size_t)(k0 + q) * EMB_ + o4];
#pragma unroll
      for (int j = 0; j < 4; ++j) {
        float x = xlds[(jt * 4 + j) * 66 + q];
        a32[j].x += x * wv.x; a32[j].y += x * wv.y;
        a32[j].z += x * wv.z; a32[j].w += x * wv.w;
      }
    }
#pragma unroll
    for (int j = 0; j < 4; ++j) {
      a64[j][0] += (double)a32[j].x; a64[j][1] += (double)a32[j].y;
      a64[j][2] += (double)a32[j].z; a64[j][3] += (double)a32[j].w;
      a32[j] = {0.f, 0.f, 0.f, 0.f};
    }
    __syncthreads();
  }
#pragma unroll
  for (int j = 0; j < 4; ++j) {
    int p = pt0 + jt * 4 + j;
#pragma unroll
    for (int i = 0; i < 4; ++i) {
      int o = o4 + i;
      double z = a64[j][i] + (double)bias[o];
      z = tanh(z);
      if (dbl_tanh) z = tanh(z);
      out[(size_t)p * EMB_ + o] = (float)z;
    }
  }
}

// ---------------------------------------------------------------- F: logits partial (all 97 r)
// 256-thread block, 128-pair tile. Double-buffered Wlin staged via async
// global_load_lds: stage(b+1) is issued BEFORE compute(b), so the DMA flies
// under ~8K cycles of FMA; ONE barrier per b (drains vmcnt + guards reuse).
// Scalar FMA (v_pk_fma_f32 is half-rate on gfx950 -- R9 evidence), summation
// order (c asc within b, b asc) identical to rounds 4-9. r=96 folded in.
__global__ __launch_bounds__(256) void k_logits_part(
    const float* __restrict__ zh, const float* __restrict__ zt,
    const float* __restrict__ Wb, float* __restrict__ part) {
  const int bid = blockIdx.x;          // 0..599
  const int s   = bid % 24;            // slab = k*2+bh  (XCD s%8 affinity)
  const int t   = bid / 24;            // p-tile 0..24
  const int k   = s >> 1, bh = s & 1;
  const int pt0 = t * 128;
  const int rt = threadIdx.x & 15;
  const int pg = threadIdx.x >> 4;     // 0..15 -> pairs pg*8+j
  const int kb0 = k * 64 + bh * 32;

  __shared__ float Wlin[2][64 * 97];   // 2 x 24832 B -> 49664 B, 3 blk/CU

  // stage slice b into buffer `buf` (1552 float4 = 6 x 256 + 16 tail)
  auto stage_w = [&](int buf, int b) {
    const float* src = Wb + (size_t)(kb0 + b) * 6208;
    float* dst = Wlin[buf];
#pragma unroll
    for (int u = 0; u < 6; ++u)
      GLOAD_LDS16(src + (u * 256 + threadIdx.x) * 4,
                  dst + (u * 256 + threadIdx.x) * 4);
    if (threadIdx.x < 16)
      GLOAD_LDS16(src + (1536 + threadIdx.x) * 4,
                  dst + (1536 + threadIdx.x) * 4);
  };

  stage_w(0, 0);

  float acc[8][6];
  float acc6[8];
#pragma unroll
  for (int j = 0; j < 8; ++j) {
    acc6[j] = 0.f;
#pragma unroll
    for (int i = 0; i < 6; ++i) acc[j][i] = 0.f;
  }

  const float* ztb  = zt + (size_t)(pt0 + pg * 8) * EMB_ + k * 64;
  const float* zh_g = zh + (size_t)(pt0 + pg * 8) * EMB_ + kb0;

  __syncthreads();                     // drains vmcnt: Wlin[0](b=0) ready

  int cur = 0;
  for (int b = 0; b < 32; ++b) {
    if (b < 31) stage_w(cur ^ 1, b + 1);   // async, overlaps compute(b)

    float zhv[8];
#pragma unroll
    for (int j = 0; j < 8; ++j) zhv[j] = zh_g[(size_t)j * EMB_ + b];

    const float* Wcur = Wlin[cur];
    for (int c0 = 0; c0 < 64; c0 += 4) {
      float4 ztv[8];
#pragma unroll
      for (int j = 0; j < 8; ++j)
        ztv[j] = *(const float4*)(ztb + (size_t)j * EMB_ + c0);
      float4 pz[8];
#pragma unroll
      for (int j = 0; j < 8; ++j) {
        pz[j].x = zhv[j] * ztv[j].x; pz[j].y = zhv[j] * ztv[j].y;
        pz[j].z = zhv[j] * ztv[j].z; pz[j].w = zhv[j] * ztv[j].w;
      }
#pragma unroll
      for (int cc = 0; cc < 4; ++cc) {
        const float* wr = &Wcur[(c0 + cc) * 97];
        float w6 = wr[96];
#pragma unroll
        for (int i = 0; i < 6; ++i) {
          float w = wr[rt + 16 * i];   // compiler ds_read_b32, 16-lane broadcast
#pragma unroll
          for (int j = 0; j < 8; ++j) {
            float pzc = (cc == 0) ? pz[j].x : (cc == 1) ? pz[j].y
                      : (cc == 2) ? pz[j].z : pz[j].w;
            acc[j][i] += pzc * w;
          }
        }
#pragma unroll
        for (int j = 0; j < 8; ++j) {
          float pzc = (cc == 0) ? pz[j].x : (cc == 1) ? pz[j].y
                    : (cc == 2) ? pz[j].z : pz[j].w;
          acc6[j] += pzc * w6;
        }
      }
    }
    __syncthreads();                   // readers of cur done + next slice landed
    cur ^= 1;
  }

  float* po = part + (size_t)s * NP_ * NREL_;
#pragma unroll
  for (int j = 0; j < 8; ++j) {
    int p = pt0 + pg * 8 + j;
#pragma unroll
    for (int i = 0; i < 6; ++i)
      po[(size_t)p * NREL_ + rt + 16 * i] = acc[j][i];
    if (rt == 0) po[(size_t)p * NREL_ + 96] = acc6[j];
  }
}

// ---------------------------------------------------------------- G: finalize
__global__ void k_final(const float* __restrict__ part, const float* __restrict__ bb,
                        float* __restrict__ out) {
  const int p = blockIdx.x;
  const int r = threadIdx.x;           // 128 threads
  __shared__ double th_s;
  __shared__ int cnt[128];
  double v = 0.0;
  if (r < NREL_) {
#pragma unroll
    for (int g = 0; g < NPART; ++g)
      v += (double)part[(size_t)g * NP_ * NREL_ + (size_t)p * NREL_ + r];
    v += (double)bb[r];
    out[(size_t)p * NREL_ + r] = (float)v;
  }
  if (r == 0) th_s = v;
  __syncthreads();
  int pred = (r >= 1 && r < NREL_ && v > th_s) ? 1 : 0;
  cnt[r] = pred;
  __syncthreads();
  for (int s = 64; s > 0; s >>= 1) {
    if (r < s) cnt[r] += cnt[r + s];
    __syncthreads();
  }
  if (r < NREL_) {
    float pv = (r == 0) ? ((cnt[0] == 0) ? 1.f : 0.f) : (float)pred;
    out[(size_t)NP_ * NREL_ + (size_t)p * NREL_ + r] = pv;
  }
}

extern "C" void kernel_launch(void* const* d_in, const int* in_sizes, int n_in,
                              void* d_out, int out_size, void* d_ws, size_t ws_size,
                              hipStream_t stream) {
  const float* seq  = (const float*)d_in[0];
  const float* att  = (const float*)d_in[1];
  const int*   mpos = (const int*)d_in[2];
  const int*   hts  = (const int*)d_in[3];
  const float* Wh   = (const float*)d_in[4];
  const float* bh   = (const float*)d_in[5];
  const float* Wt   = (const float*)d_in[6];
  const float* bt   = (const float*)d_in[7];
  const float* Wb   = (const float*)d_in[8];
  const float* bb   = (const float*)d_in[9];
  float* out = (float*)d_out;
  float* ws = (float*)d_ws;

  float* ent_emb = ws;                   // [0, 122880)
  float* ent_att = ws + 122880;          // dead after k_ht_att
  float* ht      = ws + 2088960;         // dead after k_rs
  float* rs      = ws + 5365760;         // dead after k_zht
  float* zh      = ws + 7823360;
  float* zt      = ws + 10280960;
  // part (24*3200*97 floats) aliases dead ent_att+ht+rs: [122880, 7572480)
  float* part    = ws + 122880;

  k_ent_emb<<<160, 256, 0, stream>>>(seq, mpos, ent_emb);
  k_ent_att<<<7680, 256, 0, stream>>>(att, mpos, ent_att);
  k_ht_att<<<3200, 64, 0, stream>>>(ent_att, hts, ht);
  k_rs<<<dim3(200, 3), 256, 0, stream>>>(ht, seq, rs);
  k_zht<<<dim3(200, 3), 256, 0, stream>>>(ent_emb, rs, hts, Wh, bh, zh, 0, 1);
  k_zht<<<dim3(200, 3), 256, 0, stream>>>(ent_emb, rs, hts, Wt, bt, zt, 1, 0);
  k_logits_part<<<600, 256, 0, stream>>>(zh, zt, Wb, part);
  k_final<<<3200, 128, 0, stream>>>(part, bb, out);
}